// Round 6
// baseline (436.692 us; speedup 1.0000x reference)
//
#include <hip/hip_runtime.h>

// ECGNNEdgePredictor: 512 graphs x 30 nodes, HID=64, 5 NNConv layers + MLP head.
// One block per graph, 512 threads = 8 waves, 1 block/CU (154KB dynamic LDS).
// R6 rewrite: msg aggregation factored as agg = Q @ W2' with
//   Q[d, k*64+h] = (S_k @ H)[d,h],  S_k[d,n] = sum_{e: dst=d,src=n} z[e,k]
// (k=32 row = adjacency -> folds the b2 term through the existing ones-chunk).
// Kills the per-chunk z*A VALU scaling (R5's top pipe), halves MFMA count again
// (792/layer vs 1584), reads W2 once per block (halves L2 B-traffic).
// GEMM1 (per k): Q_k^T = H^T @ S_k^T (8 MFMA), transpose via wave-private LDS;
// GEMM2: A=Q chunks, B=W2s (existing layout), 16 MFMA C-chained per k.

typedef float f32x4 __attribute__((ext_vector_type(4)));
typedef _Float16 f16x8 __attribute__((ext_vector_type(8)));
typedef _Float16 f16x4 __attribute__((ext_vector_type(4)));

#define MFMA16(a, b, c) __builtin_amdgcn_mfma_f32_16x16x32_f16((a), (b), (c), 0, 0, 0)

// ws layout (bytes) — unchanged from R5
#define WS_W2S 0u        // 5*66*64*32 f16 = 1351680 B (W2 + b2 fused, B-frag order)
#define WS_W1S 1351680u  // 5*4*32*32  f16 = 40960 B
#define WS_WRS 1392640u  // 5*2*64*32  f16 = 40960 B
#define WS_BNS 1433600u  // 320 f32 scale
#define WS_BNH 1434880u  // 320 f32 shift

// dynamic LDS layout (bytes)
#define OFF_SC   0u        // S: [33 k][32 d][40 n] f16 = 84480 (stride 40: 2-way banks, 16B-aligned frags)
#define OFF_QB   84480u    // 8 waves x [2 kh][32 d][40 h] f16 = 40960; union: zT f32[32][100], head-hid f32[64*41]
#define OFF_HHT  125440u   // H^T: [64 h][40 n] f16 = 5120 (cols 30..39 ZERO = K-padding)
#define OFF_HH   130560u   // H: [32][72] f16 = 4608
#define OFF_HF   135168u   // H fp32 master: [32][68] f32 = 8704
#define OFF_AGG  143872u   // [32][68] f32 = 8704
#define OFF_EDGE 152576u   // srcn/dstn/leadE/nextE int[96] each = 1536
#define OFF_DEG  154112u   // f32[32]
#define SMEM_BYTES 154240u

__device__ inline f16x8 ld_frag_g(const _Float16* p) {
  union { uint4 u; f16x8 f; } c;
  c.u = *(const uint4*)p;
  return c.f;
}
__device__ inline f16x8 ld_frag_s(const _Float16* p) { return *(const f16x8*)p; }

// ---------------- prep: repack weights to f16 in MFMA B-fragment order (unchanged) ----
__global__ __launch_bounds__(256) void prep_kernel(
    const float* __restrict__ W1, const float* __restrict__ W2,
    const float* __restrict__ b2, const float* __restrict__ Wr,
    const float* __restrict__ gamma, const float* __restrict__ beta,
    const float* __restrict__ rmean, const float* __restrict__ rvar,
    unsigned char* __restrict__ ws) {
  int idx = blockIdx.x * 256 + threadIdx.x;
  _Float16* W2s = (_Float16*)(ws + WS_W2S);
  _Float16* W1s = (_Float16*)(ws + WS_W1S);
  _Float16* Wrs = (_Float16*)(ws + WS_WRS);
  float* bns = (float*)(ws + WS_BNS);
  float* bnh = (float*)(ws + WS_BNH);

  if (idx < 675840) {            // W2s: j = k*64+h (k<32), j>=2048 -> b2 rows
    int l = idx / 135168, r = idx % 135168;
    int t = r / 2048, r2 = r % 2048;
    int n = r2 >> 5, s = r2 & 31;
    int j = t * 32 + s;
    float v = (j < 2048) ? W2[(l * 32 + (j >> 6)) * 4096 + (j & 63) * 64 + n]
                         : b2[l * 4096 + (j - 2048) * 64 + n];
    W2s[idx] = (_Float16)v;
  } else if (idx < 696320) {     // W1s: K = 128
    int i2 = idx - 675840;
    int l = i2 / 4096, r = i2 % 4096;
    int t = r >> 10, n = (r >> 5) & 31, s = r & 31;
    int j = t * 32 + s;
    W1s[i2] = (_Float16)W1[l * 4096 + j * 32 + n];
  } else if (idx < 716800) {     // Wrs: K = 64
    int i3 = idx - 696320;
    int l = i3 / 4096, r = i3 % 4096;
    int t = r >> 11, rem = r & 2047;
    int n = rem >> 5, s = rem & 31;
    int j = t * 32 + s;
    Wrs[i3] = (_Float16)Wr[l * 4096 + j * 64 + n];
  } else if (idx < 717120) {     // BN folded
    int i4 = idx - 716800;
    float sc = gamma[i4] * rsqrtf(rvar[i4] + 1e-5f);
    bns[i4] = sc;
    bnh[i4] = beta[i4] - rmean[i4] * sc;
  }
}

// ---------------- main: one block per graph, 512 threads = 8 waves ----------------
__global__ __launch_bounds__(512, 2) void gnn_kernel(
    const float* __restrict__ x, const int* __restrict__ bu, const int* __restrict__ bv,
    const float* __restrict__ Wp, const float* __restrict__ bp,
    const float* __restrict__ b1, const float* __restrict__ brr,
    const float* __restrict__ Wm1, const float* __restrict__ bm1,
    const float* __restrict__ Wm2, const float* __restrict__ bm2,
    const _Float16* __restrict__ W2s, const _Float16* __restrict__ W1s,
    const _Float16* __restrict__ Wrs,
    const float* __restrict__ bns, const float* __restrict__ bnh,
    float* __restrict__ out) {
  extern __shared__ unsigned char smem[];
  _Float16* Sc  = (_Float16*)(smem + OFF_SC);   // [k][d*40 + n]
  _Float16* Qb0 = (_Float16*)(smem + OFF_QB);   // per-wave [kh][d*40 + h]
  float*    zT  = (float*)(smem + OFF_QB);      // [k][100] (phase-exclusive union)
  _Float16* hHT = (_Float16*)(smem + OFF_HHT);  // [h*40 + n]
  _Float16* hH  = (_Float16*)(smem + OFF_HH);   // [n*72 + c]
  float*    hF  = (float*)(smem + OFF_HF);      // [n*68 + c]
  float*    agg = (float*)(smem + OFF_AGG);     // [n*68 + c]
  int* srcn  = (int*)(smem + OFF_EDGE);
  int* dstn  = srcn + 96;
  int* leadE = srcn + 192;
  int* nextE = srcn + 288;
  float* invdeg = (float*)(smem + OFF_DEG);

  const int tid = threadIdx.x;
  const int g = blockIdx.x;
  const int wv = tid >> 6;     // 0..7
  const int ln = tid & 63;
  const int q = ln >> 4;
  const int m16 = ln & 15;
  const f32x4 zero4 = {0.f, 0.f, 0.f, 0.f};

  // ---- init: zero S and hHT (S pads/unused entries must stay 0 forever; hHT cols 30..39 are K-padding)
  for (int u = tid; u < 21120; u += 512) ((unsigned*)(smem + OFF_SC))[u] = 0u;
  for (int u = tid; u < 1280; u += 512) ((unsigned*)(smem + OFF_HHT))[u] = 0u;
  if (tid < 96) {
    int s, d;
    if (tid < 41)      { s = bu[tid];      d = bv[tid]; }
    else if (tid < 82) { s = bv[tid - 41]; d = bu[tid - 41]; }
    else               { s = 0;            d = 0; }
    srcn[tid] = s; dstn[tid] = d;
  }
  __syncthreads();
  // lead/next chains for duplicate (dst,src) pairs (S scatter must merge them)
  if (tid < 82) {
    int s = srcn[tid], d = dstn[tid];
    int lead = 1;
    for (int e = 0; e < tid; ++e)
      if (srcn[e] == s && dstn[e] == d) { lead = 0; break; }
    leadE[tid] = lead;
    int nx = -1;
    for (int e = tid + 1; e < 82; ++e)
      if (srcn[e] == s && dstn[e] == d) { nx = e; break; }
    nextE[tid] = nx;
  }
  if (tid < 32) {
    int cnt = 0;
    for (int e = 0; e < 82; ++e) cnt += (dstn[e] == tid) ? 1 : 0;
    invdeg[tid] = 1.0f / (float)(cnt > 0 ? cnt : 1);
  }
  // projection h0 = x @ Wp + bp
  for (int u = tid; u < 30 * 64; u += 512) {
    int n = u >> 6, c = u & 63;
    float acc = bp[c];
#pragma unroll
    for (int k = 0; k < 8; ++k) acc += x[(g * 30 + n) * 8 + k] * Wp[k * 64 + c];
    hF[n * 68 + c] = acc;
    _Float16 hi = (_Float16)acc;
    hH[n * 72 + c] = hi;
    hHT[c * 40 + n] = hi;
  }
  __syncthreads();
  // S_32 = adjacency multiplicity (constant across layers; pairs the b2/ones chunk)
  if (tid < 82 && leadE[tid]) {
    float cnt = 1.f;
    int nx = nextE[tid];
    while (nx >= 0) { cnt += 1.f; nx = nextE[nx]; }
    Sc[32 * 1280 + dstn[tid] * 40 + srcn[tid]] = (_Float16)cnt;
  }
  __syncthreads();

  for (int l = 0; l < 5; ++l) {
    // ---- phase 1: zero agg + z-GEMM -> zT[k][e] (f32)
    for (int u = tid; u < 32 * 68; u += 512) agg[u] = 0.f;
    {
      int nt = wv & 1, g2 = wv >> 1;
      int ncol = nt * 16 + m16;
      f16x8 bf[4];
#pragma unroll
      for (int t = 0; t < 4; ++t)
        bf[t] = ld_frag_g(W1s + ((l * 4 + t) * 32 + ncol) * 32 + q * 8);
      float b1v = b1[l * 32 + ncol];
#pragma unroll
      for (int mi = 0; mi < 2; ++mi) {
        int mt = g2 + mi * 4;
        if (mt < 6) {
          int e = mt * 16 + m16;
          int sn = srcn[e], dn = dstn[e];
          f32x4 acc = zero4;
#pragma unroll
          for (int t = 0; t < 4; ++t) {
            int nd = (t < 2) ? sn : dn;
            acc = MFMA16(ld_frag_s(hH + nd * 72 + (t & 1) * 32 + q * 8), bf[t], acc);
          }
#pragma unroll
          for (int r = 0; r < 4; ++r) {
            int e2 = mt * 16 + q * 4 + r;
            float v = fmaxf(acc[r] + b1v, 0.f);
            if (e2 < 82) zT[ncol * 100 + e2] = v;
          }
        }
      }
    }
    __syncthreads();

    // ---- phase 2: scatter z into dense S (lead edges merge duplicate pairs)
    for (int it = tid; it < 82 * 32; it += 512) {
      int k = it / 82, e = it - k * 82;
      if (leadE[e]) {
        float v = zT[k * 100 + e];
        int nx = nextE[e];
        while (nx >= 0) { v += zT[k * 100 + nx]; nx = nextE[nx]; }
        Sc[k * 1280 + dstn[e] * 40 + srcn[e]] = (_Float16)v;
      }
    }
    __syncthreads();

    // ---- phase 3: per-wave k-subset: GEMM1 (Q_k^T = H^T @ S_k^T) -> Qb -> GEMM2 (Q @ W2')
    {
      f16x8 aT[4];
#pragma unroll
      for (int mt = 0; mt < 4; ++mt)
        aT[mt] = ld_frag_s(hHT + (mt * 16 + m16) * 40 + q * 8);
      _Float16* Qb = Qb0 + wv * 2560;
      const _Float16* WbL = W2s + (size_t)l * 135168;
      f32x4 macc[2][4];
#pragma unroll
      for (int mt = 0; mt < 2; ++mt)
#pragma unroll
        for (int nt = 0; nt < 4; ++nt) macc[mt][nt] = zero4;

      for (int k = wv; k < 33; k += 8) {
        // B2 global loads early (L2 latency overlaps GEMM1)
        f16x8 B2[2][4];
#pragma unroll
        for (int s = 0; s < 2; ++s)
#pragma unroll
          for (int nt = 0; nt < 4; ++nt)
            B2[s][nt] = ld_frag_g(WbL + ((size_t)(2 * k + s) * 64 + nt * 16 + m16) * 32 + q * 8);
        // GEMM1: C[h][d] = H^T @ S_k^T ; A rows h (4 mt), B cols d (2 halves), K = src n
        f16x8 bS0 = ld_frag_s(Sc + k * 1280 + m16 * 40 + q * 8);
        f16x8 bS1 = ld_frag_s(Sc + k * 1280 + (16 + m16) * 40 + q * 8);
        f32x4 c1[4][2];
#pragma unroll
        for (int mt = 0; mt < 4; ++mt) {
          c1[mt][0] = MFMA16(aT[mt], bS0, zero4);
          c1[mt][1] = MFMA16(aT[mt], bS1, zero4);
        }
        // transpose via wave-private Qb: write Q[d][h] (C cols -> rows)
#pragma unroll
        for (int mt = 0; mt < 4; ++mt)
#pragma unroll
          for (int nt2 = 0; nt2 < 2; ++nt2) {
            f16x4 qv;
#pragma unroll
            for (int r = 0; r < 4; ++r) qv[r] = (_Float16)c1[mt][nt2][r];
            *(f16x4*)(Qb + (mt >> 1) * 1280 + (nt2 * 16 + m16) * 40 + (mt & 1) * 16 + q * 4) = qv;
          }
        // GEMM2: agg-partial += Q[:, k-chunk] @ W2'[k-chunk, :]
        f16x8 A2[2][2];
#pragma unroll
        for (int mt = 0; mt < 2; ++mt)
#pragma unroll
          for (int kh = 0; kh < 2; ++kh)
            A2[mt][kh] = ld_frag_s(Qb + kh * 1280 + (mt * 16 + m16) * 40 + q * 8);
#pragma unroll
        for (int nt = 0; nt < 4; ++nt) {
          macc[0][nt] = MFMA16(A2[0][0], B2[0][nt], macc[0][nt]);
          macc[0][nt] = MFMA16(A2[0][1], B2[1][nt], macc[0][nt]);
          macc[1][nt] = MFMA16(A2[1][0], B2[0][nt], macc[1][nt]);
          macc[1][nt] = MFMA16(A2[1][1], B2[1][nt], macc[1][nt]);
        }
      }
      // reduce k-partials across waves
#pragma unroll
      for (int mt = 0; mt < 2; ++mt)
#pragma unroll
        for (int r = 0; r < 4; ++r) {
          int row = mt * 16 + q * 4 + r;
          if (row < 30)
#pragma unroll
            for (int nt = 0; nt < 4; ++nt)
              atomicAdd(&agg[row * 68 + nt * 16 + m16], macc[mt][nt][r]);
        }
    }
    __syncthreads();

    // ---- phase 4: h = relu(BN(agg/deg + h@Wr + br)) + h ; wave w owns 16x16 tile
    {
      int ncol = (wv & 3) * 16 + m16;
      int mt = wv >> 2;
      float scl = bns[l * 64 + ncol];
      float sft = bnh[l * 64 + ncol];
      float brb = brr[l * 64 + ncol];
      f16x8 wb0 = ld_frag_g(Wrs + ((l * 2 + 0) * 64 + ncol) * 32 + q * 8);
      f16x8 wb1 = ld_frag_g(Wrs + ((l * 2 + 1) * 64 + ncol) * 32 + q * 8);
      f32x4 acc = zero4;
      acc = MFMA16(ld_frag_s(hH + (mt * 16 + m16) * 72 + q * 8), wb0, acc);
      acc = MFMA16(ld_frag_s(hH + (mt * 16 + m16) * 72 + 32 + q * 8), wb1, acc);
      __syncthreads();  // all root-GEMM reads of hH done before any h overwrite
#pragma unroll
      for (int r = 0; r < 4; ++r) {
        int row = mt * 16 + q * 4 + r;
        if (row < 30) {
          float v = agg[row * 68 + ncol] * invdeg[row] + acc[r] + brb;
          v = v * scl + sft;
          float hn = fmaxf(v, 0.f) + hF[row * 68 + ncol];
          hF[row * 68 + ncol] = hn;
          _Float16 hi = (_Float16)hn;
          hH[row * 72 + ncol] = hi;
          hHT[ncol * 40 + row] = hi;
        }
      }
    }
    __syncthreads();
  }

  // ---- head: out = relu([h_u|h_v] @ Wm1 + bm1) @ Wm2 + bm2 (fp32, from hF)
  float* hid = (float*)(smem + OFF_QB);  // [c*41 + i]
  for (int u = tid; u < 41 * 64; u += 512) {
    int i = u >> 6, c = u & 63;
    int ui = srcn[i], vi = dstn[i];
    float acc = bm1[c];
#pragma unroll 4
    for (int k = 0; k < 64; ++k)
      acc += hF[ui * 68 + k] * Wm1[k * 64 + c] + hF[vi * 68 + k] * Wm1[(64 + k) * 64 + c];
    hid[c * 41 + i] = fmaxf(acc, 0.f);
  }
  __syncthreads();
  if (tid < 41) {
    float acc = bm2[0];
    for (int c = 0; c < 64; ++c) acc += hid[c * 41 + tid] * Wm2[c];
    out[g * 41 + tid] = acc;
  }
}

extern "C" void kernel_launch(void* const* d_in, const int* in_sizes, int n_in,
                              void* d_out, int out_size, void* d_ws, size_t ws_size,
                              hipStream_t stream) {
  const float* x   = (const float*)d_in[0];
  // d_in[1] = edge_index (rebuilt from branch lists), d_in[4] = num_graphs (const 512)
  const int* bu    = (const int*)d_in[2];
  const int* bv    = (const int*)d_in[3];
  const float* Wp  = (const float*)d_in[5];
  const float* bp  = (const float*)d_in[6];
  const float* W1  = (const float*)d_in[7];
  const float* b1  = (const float*)d_in[8];
  const float* W2  = (const float*)d_in[9];
  const float* b2  = (const float*)d_in[10];
  const float* Wr  = (const float*)d_in[11];
  const float* br  = (const float*)d_in[12];
  const float* gm  = (const float*)d_in[13];
  const float* bt  = (const float*)d_in[14];
  const float* rm  = (const float*)d_in[15];
  const float* rv  = (const float*)d_in[16];
  const float* Wm1 = (const float*)d_in[17];
  const float* bm1 = (const float*)d_in[18];
  const float* Wm2 = (const float*)d_in[19];
  const float* bm2 = (const float*)d_in[20];
  unsigned char* ws = (unsigned char*)d_ws;
  float* out = (float*)d_out;

  // allow >64KB dynamic LDS (idempotent, not a stream op — graph-capture safe)
  hipFuncSetAttribute(reinterpret_cast<const void*>(gnn_kernel),
                      hipFuncAttributeMaxDynamicSharedMemorySize, (int)SMEM_BYTES);

  prep_kernel<<<2802, 256, 0, stream>>>(W1, W2, b2, Wr, gm, bt, rm, rv, ws);
  gnn_kernel<<<512, 512, SMEM_BYTES, stream>>>(
      x, bu, bv, Wp, bp, b1, br, Wm1, bm1, Wm2, bm2,
      (const _Float16*)(ws + WS_W2S),
      (const _Float16*)(ws + WS_W1S),
      (const _Float16*)(ws + WS_WRS),
      (const float*)(ws + WS_BNS),
      (const float*)(ws + WS_BNH),
      out);
}

// Round 7
// 271.701 us; speedup vs baseline: 1.6073x; 1.6073x over previous
//
#include <hip/hip_runtime.h>

// ECGNNEdgePredictor: 512 graphs x 30 nodes, HID=64, 5 NNConv layers + MLP head.
// One block per graph, 512 threads = 8 waves, 2 blocks/CU.
// R7 = R5 structure (best known) + fixes:
//  - prep: source-linear (coalesced) W2/b2 reads, scattered 2B writes (was 256B-stride
//    gather reads -> ~70us of the bench total).
//  - msg loop: ring-4 B prefetch, chunk-32 (b2/ones) specialized unscaled -> 32 iters
//    unroll-4 (no pipeline movs); z edge-major zE[e][k] -> ds_read_b128 per 4 chunks;
//    pad edges dropped by scatter guard (e<82) instead of z zeroing.
//  - root-GEMM hoisted before msg (reads pre-update h) -> 3 barriers/layer, no race.
// msg GEMM fused as P @ W2' with P[e,k*64+h] = z[e,k]*h_src[e,h] (+ones col for b2);
// z folded into A-operand (f16) -> pure MFMA->MFMA C-accumulation. fp32 master h;
// hi/lo f16 split on z-GEMM and root-GEMM A-operands keeps h at ~fp32 there.

typedef float f32x4 __attribute__((ext_vector_type(4)));
typedef _Float16 f16x8 __attribute__((ext_vector_type(8)));

#define MFMA16(a, b, c) __builtin_amdgcn_mfma_f32_16x16x32_f16((a), (b), (c), 0, 0, 0)

// ws layout (bytes)
#define WS_W2S 0u        // 5*66*64*32 f16 = 1351680 B (W2 + b2 fused, B-frag order)
#define WS_W1S 1351680u  // 5*4*32*32  f16 = 40960 B
#define WS_WRS 1392640u  // 5*2*64*32  f16 = 40960 B
#define WS_BNS 1433600u  // 320 f32 scale
#define WS_BNH 1434880u  // 320 f32 shift

__device__ inline f16x8 ld_frag_g(const _Float16* p) {
  union { uint4 u; f16x8 f; } c;
  c.u = *(const uint4*)p;
  return c.f;
}
__device__ inline f16x8 ld_frag_s(const _Float16* p) { return *(const f16x8*)p; }

// ---------------- prep: repack weights to f16 in MFMA B-fragment order ----------------
// B-frag layout per 16x16x32 k-step t: elem(t, n, q, i) = B[j = t*32 + q*8 + i][n].
// R7: W2/b2 sections iterate SOURCE-linear (n innermost) -> coalesced reads.
__global__ __launch_bounds__(256) void prep_kernel(
    const float* __restrict__ W1, const float* __restrict__ W2,
    const float* __restrict__ b2, const float* __restrict__ Wr,
    const float* __restrict__ gamma, const float* __restrict__ beta,
    const float* __restrict__ rmean, const float* __restrict__ rvar,
    unsigned char* __restrict__ ws) {
  int idx = blockIdx.x * 256 + threadIdx.x;
  _Float16* W2s = (_Float16*)(ws + WS_W2S);
  _Float16* W1s = (_Float16*)(ws + WS_W1S);
  _Float16* Wrs = (_Float16*)(ws + WS_WRS);
  float* bns = (float*)(ws + WS_BNS);
  float* bnh = (float*)(ws + WS_BNH);

  if (idx < 655360) {            // W2 source-linear: (l,k,h,n), n innermost, j = k*64+h
    int n = idx & 63, h = (idx >> 6) & 63, k = (idx >> 12) & 31, l = idx >> 17;
    int j = k * 64 + h;
    W2s[(size_t)l * 135168 + (j >> 5) * 2048 + n * 32 + (j & 31)] = (_Float16)W2[idx];
  } else if (idx < 675840) {     // b2 source-linear: j = 2048 + h
    int i = idx - 655360;
    int n = i & 63, h = (i >> 6) & 63, l = i >> 12;
    int j = 2048 + h;
    W2s[(size_t)l * 135168 + (j >> 5) * 2048 + n * 32 + (j & 31)] = (_Float16)b2[i];
  } else if (idx < 696320) {     // W1s: K = 128 (small, keep dest-linear)
    int i2 = idx - 675840;
    int l = i2 / 4096, r = i2 % 4096;
    int t = r >> 10, n = (r >> 5) & 31, s = r & 31;
    int j = t * 32 + s;
    W1s[i2] = (_Float16)W1[l * 4096 + j * 32 + n];
  } else if (idx < 716800) {     // Wrs: K = 64 (small)
    int i3 = idx - 696320;
    int l = i3 / 4096, r = i3 % 4096;
    int t = r >> 11, rem = r & 2047;
    int n = rem >> 5, s = rem & 31;
    int j = t * 32 + s;
    Wrs[i3] = (_Float16)Wr[l * 4096 + j * 64 + n];
  } else if (idx < 717120) {     // BN folded
    int i4 = idx - 716800;
    float sc = gamma[i4] * rsqrtf(rvar[i4] + 1e-5f);
    bns[i4] = sc;
    bnh[i4] = beta[i4] - rmean[i4] * sc;
  }
}

// ---------------- main: one block per graph, 512 threads = 8 waves ----------------
__global__ __launch_bounds__(512, 4) void gnn_kernel(
    const float* __restrict__ x, const int* __restrict__ bu, const int* __restrict__ bv,
    const float* __restrict__ Wp, const float* __restrict__ bp,
    const float* __restrict__ b1, const float* __restrict__ brr,
    const float* __restrict__ Wm1, const float* __restrict__ bm1,
    const float* __restrict__ Wm2, const float* __restrict__ bm2,
    const _Float16* __restrict__ W2s, const _Float16* __restrict__ W1s,
    const _Float16* __restrict__ Wrs,
    const float* __restrict__ bns, const float* __restrict__ bnh,
    float* __restrict__ out) {
  __shared__ __align__(16) float hF[32][68];         // fp32 master h
  __shared__ __align__(16) _Float16 hH[32][72];      // f16 hi part of h
  __shared__ __align__(16) _Float16 hL[32][72];      // f16 lo part (h - hi)
  __shared__ __align__(16) float zE[96][36];         // z edge-major [e][k]
  __shared__ __align__(16) float agg[32][68];        // scatter accumulator
  __shared__ int srcn[96], dstn[96];
  __shared__ float invdeg[32];

  const int tid = threadIdx.x;
  const int g = blockIdx.x;
  const int wv = tid >> 6;     // 0..7
  const int ln = tid & 63;
  const int q = ln >> 4;
  const int m16 = ln & 15;
  const f32x4 zero4 = {0.f, 0.f, 0.f, 0.f};

  // ---- init: edge lists (both directions), pad rows, agg zero
  if (tid < 96) {
    int s, d;
    if (tid < 41)      { s = bu[tid];      d = bv[tid]; }
    else if (tid < 82) { s = bv[tid - 41]; d = bu[tid - 41]; }
    else               { s = 0;            d = 0; }
    srcn[tid] = s; dstn[tid] = d;
  }
  if (tid < 136) { hF[30 + tid / 68][tid % 68] = 0.f; }
  if (tid < 144) {
    hH[30 + tid / 72][tid % 72] = (_Float16)0.f;
    hL[30 + tid / 72][tid % 72] = (_Float16)0.f;
  }
  for (int u = tid; u < 32 * 68; u += 512) ((float*)agg)[u] = 0.f;
  __syncthreads();
  if (tid < 32) {
    int cnt = 0;
    for (int e = 0; e < 82; ++e) cnt += (dstn[e] == tid) ? 1 : 0;
    invdeg[tid] = 1.0f / (float)(cnt > 0 ? cnt : 1);
  }
  // ---- projection h0 = x @ Wp + bp (fp32, then split hi/lo)
  for (int u = tid; u < 30 * 64; u += 512) {
    int n = u >> 6, c = u & 63;
    float acc = bp[c];
#pragma unroll
    for (int k = 0; k < 8; ++k) acc += x[(g * 30 + n) * 8 + k] * Wp[k * 64 + c];
    hF[n][c] = acc;
    _Float16 hi = (_Float16)acc;
    hH[n][c] = hi;
    hL[n][c] = (_Float16)(acc - (float)hi);
  }
  __syncthreads();

  for (int l = 0; l < 5; ++l) {
    // ======== phase A: root-GEMM (pre-update h) + z-GEMM ========
    const int ncolR = (wv & 3) * 16 + m16;
    const int mtR = wv >> 2;
    float scl = bns[l * 64 + ncolR];
    float sft = bnh[l * 64 + ncolR];
    float brb = brr[l * 64 + ncolR];
    f32x4 racc = zero4;
    {
      f16x8 wb0 = ld_frag_g(Wrs + ((l * 2 + 0) * 64 + ncolR) * 32 + q * 8);
      f16x8 wb1 = ld_frag_g(Wrs + ((l * 2 + 1) * 64 + ncolR) * 32 + q * 8);
      racc = MFMA16(ld_frag_s(&hH[mtR * 16 + m16][q * 8]), wb0, racc);
      racc = MFMA16(ld_frag_s(&hH[mtR * 16 + m16][32 + q * 8]), wb1, racc);
      racc = MFMA16(ld_frag_s(&hL[mtR * 16 + m16][q * 8]), wb0, racc);
      racc = MFMA16(ld_frag_s(&hL[mtR * 16 + m16][32 + q * 8]), wb1, racc);
    }
    // z = relu([h_src|h_dst] @ W1 + b1): 12 tiles over 8 waves -> zE[e][k]
    {
      int ntz = wv & 1, g2 = wv >> 1;
      int ncol = ntz * 16 + m16;
      f16x8 bf[4];
#pragma unroll
      for (int t = 0; t < 4; ++t)
        bf[t] = ld_frag_g(W1s + ((l * 4 + t) * 32 + ncol) * 32 + q * 8);
      float b1v = b1[l * 32 + ncol];
#pragma unroll
      for (int mi = 0; mi < 2; ++mi) {
        int mt = g2 + mi * 4;
        if (mt < 6) {
          int e = mt * 16 + m16;
          int sn = srcn[e], dn = dstn[e];
          f32x4 acc = zero4;
#pragma unroll
          for (int t = 0; t < 4; ++t) {
            int nd = (t < 2) ? sn : dn;
            acc = MFMA16(ld_frag_s(&hH[nd][(t & 1) * 32 + q * 8]), bf[t], acc);
          }
#pragma unroll
          for (int t = 0; t < 4; ++t) {
            int nd = (t < 2) ? sn : dn;
            acc = MFMA16(ld_frag_s(&hL[nd][(t & 1) * 32 + q * 8]), bf[t], acc);
          }
#pragma unroll
          for (int r = 0; r < 4; ++r) {
            int e2 = mt * 16 + q * 4 + r;
            zE[e2][ncol] = fmaxf(acc[r] + b1v, 0.f);  // pads written but never scattered
          }
        }
      }
    }
    __syncthreads();

    // ======== phase B: msg GEMM [96 x 2112] x [2112 x 64] ========
    // Wave w: N-cols [(w&3)*16,+16), M-half (w>>2). Chunk 32 (b2/ones) unscaled first;
    // chunks 0..31 with z folded into A, ring-4 B prefetch, unroll 4, b128 z reads.
    {
      int nt = wv & 3, mh = wv >> 2;
      int e0 = mh * 48 + m16, e1 = e0 + 16, e2 = e0 + 32;
      f16x8 hA[3][2];
      {
        int s0 = srcn[e0], s1 = srcn[e1], s2 = srcn[e2];
        hA[0][0] = ld_frag_s(&hH[s0][q * 8]); hA[0][1] = ld_frag_s(&hH[s0][32 + q * 8]);
        hA[1][0] = ld_frag_s(&hH[s1][q * 8]); hA[1][1] = ld_frag_s(&hH[s1][32 + q * 8]);
        hA[2][0] = ld_frag_s(&hH[s2][q * 8]); hA[2][1] = ld_frag_s(&hH[s2][32 + q * 8]);
      }
      f32x4 macc[3] = {zero4, zero4, zero4};
      const _Float16* Wb = W2s + (size_t)l * 135168 + (nt * 16 + m16) * 32 + q * 8;
      f16x8 r0a = ld_frag_g(Wb + (size_t)0 * 2048), r0b = ld_frag_g(Wb + (size_t)1 * 2048);
      f16x8 r1a = ld_frag_g(Wb + (size_t)2 * 2048), r1b = ld_frag_g(Wb + (size_t)3 * 2048);
      f16x8 r2a = ld_frag_g(Wb + (size_t)4 * 2048), r2b = ld_frag_g(Wb + (size_t)5 * 2048);
      f16x8 r3a, r3b;
      f16x8 Bz0 = ld_frag_g(Wb + (size_t)64 * 2048), Bz1 = ld_frag_g(Wb + (size_t)65 * 2048);
      macc[0] = MFMA16(hA[0][0], Bz0, macc[0]); macc[0] = MFMA16(hA[0][1], Bz1, macc[0]);
      macc[1] = MFMA16(hA[1][0], Bz0, macc[1]); macc[1] = MFMA16(hA[1][1], Bz1, macc[1]);
      macc[2] = MFMA16(hA[2][0], Bz0, macc[2]); macc[2] = MFMA16(hA[2][1], Bz1, macc[2]);
      for (int cb = 0; cb < 32; cb += 4) {
        f32x4 zb0 = *(const f32x4*)&zE[e0][cb];
        f32x4 zb1 = *(const f32x4*)&zE[e1][cb];
        f32x4 zb2 = *(const f32x4*)&zE[e2][cb];
        { // p=0: use slot0 (cb), prefetch cb+3 -> slot3
          if (cb + 3 < 32) { r3a = ld_frag_g(Wb + (size_t)(2 * cb + 6) * 2048);
                             r3b = ld_frag_g(Wb + (size_t)(2 * cb + 7) * 2048); }
          _Float16 z0 = (_Float16)zb0[0], z1 = (_Float16)zb1[0], z2 = (_Float16)zb2[0];
          macc[0] = MFMA16(hA[0][0] * z0, r0a, macc[0]); macc[0] = MFMA16(hA[0][1] * z0, r0b, macc[0]);
          macc[1] = MFMA16(hA[1][0] * z1, r0a, macc[1]); macc[1] = MFMA16(hA[1][1] * z1, r0b, macc[1]);
          macc[2] = MFMA16(hA[2][0] * z2, r0a, macc[2]); macc[2] = MFMA16(hA[2][1] * z2, r0b, macc[2]);
        }
        { // p=1: use slot1 (cb+1), prefetch cb+4 -> slot0
          if (cb + 4 < 32) { r0a = ld_frag_g(Wb + (size_t)(2 * cb + 8) * 2048);
                             r0b = ld_frag_g(Wb + (size_t)(2 * cb + 9) * 2048); }
          _Float16 z0 = (_Float16)zb0[1], z1 = (_Float16)zb1[1], z2 = (_Float16)zb2[1];
          macc[0] = MFMA16(hA[0][0] * z0, r1a, macc[0]); macc[0] = MFMA16(hA[0][1] * z0, r1b, macc[0]);
          macc[1] = MFMA16(hA[1][0] * z1, r1a, macc[1]); macc[1] = MFMA16(hA[1][1] * z1, r1b, macc[1]);
          macc[2] = MFMA16(hA[2][0] * z2, r1a, macc[2]); macc[2] = MFMA16(hA[2][1] * z2, r1b, macc[2]);
        }
        { // p=2: use slot2 (cb+2), prefetch cb+5 -> slot1
          if (cb + 5 < 32) { r1a = ld_frag_g(Wb + (size_t)(2 * cb + 10) * 2048);
                             r1b = ld_frag_g(Wb + (size_t)(2 * cb + 11) * 2048); }
          _Float16 z0 = (_Float16)zb0[2], z1 = (_Float16)zb1[2], z2 = (_Float16)zb2[2];
          macc[0] = MFMA16(hA[0][0] * z0, r2a, macc[0]); macc[0] = MFMA16(hA[0][1] * z0, r2b, macc[0]);
          macc[1] = MFMA16(hA[1][0] * z1, r2a, macc[1]); macc[1] = MFMA16(hA[1][1] * z1, r2b, macc[1]);
          macc[2] = MFMA16(hA[2][0] * z2, r2a, macc[2]); macc[2] = MFMA16(hA[2][1] * z2, r2b, macc[2]);
        }
        { // p=3: use slot3 (cb+3), prefetch cb+6 -> slot2
          if (cb + 6 < 32) { r2a = ld_frag_g(Wb + (size_t)(2 * cb + 12) * 2048);
                             r2b = ld_frag_g(Wb + (size_t)(2 * cb + 13) * 2048); }
          _Float16 z0 = (_Float16)zb0[3], z1 = (_Float16)zb1[3], z2 = (_Float16)zb2[3];
          macc[0] = MFMA16(hA[0][0] * z0, r3a, macc[0]); macc[0] = MFMA16(hA[0][1] * z0, r3b, macc[0]);
          macc[1] = MFMA16(hA[1][0] * z1, r3a, macc[1]); macc[1] = MFMA16(hA[1][1] * z1, r3b, macc[1]);
          macc[2] = MFMA16(hA[2][0] * z2, r3a, macc[2]); macc[2] = MFMA16(hA[2][1] * z2, r3b, macc[2]);
        }
      }
      // guarded scatter (pad edges e>=82 discarded -> no z zeroing needed)
#pragma unroll
      for (int mi = 0; mi < 3; ++mi) {
#pragma unroll
        for (int r = 0; r < 4; ++r) {
          int e = mh * 48 + mi * 16 + q * 4 + r;
          if (e < 82) atomicAdd(&agg[dstn[e]][nt * 16 + m16], macc[mi][r]);
        }
      }
    }
    __syncthreads();

    // ======== phase C: h = relu(BN(agg/deg + racc + br)) + h ; re-zero agg ========
    {
#pragma unroll
      for (int r = 0; r < 4; ++r) {
        int row = mtR * 16 + q * 4 + r;
        if (row < 30) {
          float v = agg[row][ncolR] * invdeg[row] + racc[r] + brb;
          agg[row][ncolR] = 0.f;
          v = v * scl + sft;
          float hn = fmaxf(v, 0.f) + hF[row][ncolR];
          hF[row][ncolR] = hn;
          _Float16 hi = (_Float16)hn;
          hH[row][ncolR] = hi;
          hL[row][ncolR] = (_Float16)(hn - (float)hi);
        }
      }
    }
    __syncthreads();
  }

  // ---- head: out = relu([h_u|h_v] @ Wm1 + bm1) @ Wm2 + bm2 (fp32, from hF)
  float* hid = &zE[0][0];  // reuse as [c*41 + i], 2624 <= 3456 floats
  for (int u = tid; u < 41 * 64; u += 512) {
    int i = u >> 6, c = u & 63;
    int ui = srcn[i], vi = dstn[i];
    float acc = bm1[c];
#pragma unroll 4
    for (int k = 0; k < 64; ++k)
      acc += hF[ui][k] * Wm1[k * 64 + c] + hF[vi][k] * Wm1[(64 + k) * 64 + c];
    hid[c * 41 + i] = fmaxf(acc, 0.f);
  }
  __syncthreads();
  if (tid < 41) {
    float acc = bm2[0];
    for (int c = 0; c < 64; ++c) acc += hid[c * 41 + tid] * Wm2[c];
    out[g * 41 + tid] = acc;
  }
}

extern "C" void kernel_launch(void* const* d_in, const int* in_sizes, int n_in,
                              void* d_out, int out_size, void* d_ws, size_t ws_size,
                              hipStream_t stream) {
  const float* x   = (const float*)d_in[0];
  // d_in[1] = edge_index (rebuilt from branch lists), d_in[4] = num_graphs (const 512)
  const int* bu    = (const int*)d_in[2];
  const int* bv    = (const int*)d_in[3];
  const float* Wp  = (const float*)d_in[5];
  const float* bp  = (const float*)d_in[6];
  const float* W1  = (const float*)d_in[7];
  const float* b1  = (const float*)d_in[8];
  const float* W2  = (const float*)d_in[9];
  const float* b2  = (const float*)d_in[10];
  const float* Wr  = (const float*)d_in[11];
  const float* br  = (const float*)d_in[12];
  const float* gm  = (const float*)d_in[13];
  const float* bt  = (const float*)d_in[14];
  const float* rm  = (const float*)d_in[15];
  const float* rv  = (const float*)d_in[16];
  const float* Wm1 = (const float*)d_in[17];
  const float* bm1 = (const float*)d_in[18];
  const float* Wm2 = (const float*)d_in[19];
  const float* bm2 = (const float*)d_in[20];
  unsigned char* ws = (unsigned char*)d_ws;
  float* out = (float*)d_out;

  prep_kernel<<<2802, 256, 0, stream>>>(W1, W2, b2, Wr, gm, bt, rm, rv, ws);
  gnn_kernel<<<512, 512, 0, stream>>>(
      x, bu, bv, Wp, bp, b1, br, Wm1, bm1, Wm2, bm2,
      (const _Float16*)(ws + WS_W2S),
      (const _Float16*)(ws + WS_W1S),
      (const _Float16*)(ws + WS_WRS),
      (const float*)(ws + WS_BNS),
      (const float*)(ws + WS_BNH),
      out);
}